// Round 1
// 602.678 us; speedup vs baseline: 1.1057x; 1.1057x over previous
//
#include <hip/hip_runtime.h>
#include <cstdint>

// ---- types ----
typedef short bf16x8 __attribute__((ext_vector_type(8)));        // 8 bf16 in 4 VGPRs
typedef unsigned short u16x8 __attribute__((ext_vector_type(8)));
typedef float f32x4 __attribute__((ext_vector_type(4)));
typedef __attribute__((address_space(3))) uint32_t lds_u32;
typedef const __attribute__((address_space(1))) uint32_t gbl_u32;

// fp32 -> bf16 bits, round-to-nearest-even
__device__ __forceinline__ unsigned short f2bf(float f) {
  union { float f; uint32_t u; } c; c.f = f;
  uint32_t u = c.u;
  return (unsigned short)((u + 0x7fffu + ((u >> 16) & 1u)) >> 16);
}

// ---- x fp32 -> bf16, 8 elems/thread ----
__global__ void cvt_x_kernel(const float* __restrict__ x,
                             unsigned short* __restrict__ y, long n) {
  long t = (long)blockIdx.x * blockDim.x + threadIdx.x;
  long base = t * 8;
  if (base >= n) return;
  const float4* p = (const float4*)(x + base);
  float4 f0 = p[0], f1 = p[1];
  u16x8 v;
  v[0] = f2bf(f0.x); v[1] = f2bf(f0.y); v[2] = f2bf(f0.z); v[3] = f2bf(f0.w);
  v[4] = f2bf(f1.x); v[5] = f2bf(f1.y); v[6] = f2bf(f1.z); v[7] = f2bf(f1.w);
  *(u16x8*)(y + base) = v;
}

// ---- W dequant: bf16(lut[idx] * scale), 8 elems/thread ----
__global__ void dequant_kernel(const int* __restrict__ idx,
                               const float* __restrict__ lut,
                               const float* __restrict__ scale,
                               unsigned short* __restrict__ w, long n) {
  __shared__ unsigned short slut[16];
  if (threadIdx.x < 15) slut[threadIdx.x] = f2bf(lut[threadIdx.x] * scale[0]);
  __syncthreads();
  long t = (long)blockIdx.x * blockDim.x + threadIdx.x;
  long base = t * 8;
  if (base >= n) return;
  const int4* p = (const int4*)(idx + base);
  int4 i0 = p[0], i1 = p[1];
  u16x8 v;
  v[0] = slut[i0.x]; v[1] = slut[i0.y]; v[2] = slut[i0.z]; v[3] = slut[i0.w];
  v[4] = slut[i1.x]; v[5] = slut[i1.y]; v[6] = slut[i1.z]; v[7] = slut[i1.w];
  *(u16x8*)(w + base) = v;
}

// ============================================================================
// bf16 NT-GEMM, 256x256 tile, BK=64, 8 waves (2Mx4N), 8-phase counted-vmcnt
// schedule (T1+T3+T4+T5 per guide §5.5). LDS per buffer: 4 regions of 16 KiB:
//   r0 = A ks0 [256][32], r1 = A ks1, r2 = B ks0, r3 = B ks1   (kstep-major)
// Swizzle (involution): stored_chunk = chunk ^ (row_bit3), i.e. byte ^=
// ((byte>>9)&1)<<4 within a region — applied on the global SOURCE of
// global_load_lds (dest stays linear, m104) and on the ds_read address.
// Staging schedule (tile t, buf d=t&1): ph1->B1(t+1), ph2->A1(t+1),
// ph3->A0(t+2) (region dead after ph1), ph4->B0(t+2) (dead after ph2),
// vmcnt(4) once per K-tile => next tile's 4 halves guaranteed, 2 halves
// (4 loads) stay in flight across the barrier. Tail stages are clamped
// dummies (NOT skipped — they keep the vmcnt counts exact).
// ============================================================================

__device__ __forceinline__ void bar() {
  asm volatile("" ::: "memory");
  __builtin_amdgcn_s_barrier();
  asm volatile("" ::: "memory");
}

// One half-tile = 256 rows x 32 k of A or B: 2 x global_load_lds(16B)/thread.
// dst (u32 units): D*65536B + R*16384B + t*16B; 2nd load = rows 128..255.
#define STAGE(D, R, G, KOFF)                                                  \
  do {                                                                        \
    lds_u32* dst_ = (lds_u32*)(&lds[0]) + (D) * 16384 + (R) * 4096 + t * 4;   \
    const unsigned short* s_ = (G) + (KOFF);                                  \
    __builtin_amdgcn_global_load_lds((gbl_u32*)(s_), dst_, 16, 0, 0);         \
    __builtin_amdgcn_global_load_lds((gbl_u32*)(s_ + (size_t)128 * 2048),     \
                                     dst_ + 2048, 16, 0, 0);                  \
  } while (0)

template <int D>
__device__ __forceinline__ void ktile(int T, unsigned short* lds,
                                      f32x4 (&acc)[8][4],
                                      const unsigned short* gA,
                                      const unsigned short* gB, int t,
                                      int aoff, int boff) {
  constexpr int NT = 32;
  const int c1 = (T + 1 < NT) ? (T + 1) : (NT - 1);
  const int c2 = (T + 2 < NT) ? (T + 2) : (NT - 1);
  const int k1 = c1 * 64, k2 = c2 * 64;

  const unsigned short* lA0 = &lds[D * 32768 + aoff];          // A ks0
  const unsigned short* lA1 = &lds[D * 32768 + 8192 + aoff];   // A ks1
  const unsigned short* lB0 = &lds[D * 32768 + 16384 + boff];  // B ks0
  const unsigned short* lB1 = &lds[D * 32768 + 24576 + boff];  // B ks1

  bf16x8 afr[8], b0, b1;

  // ---- phase 1: ks0, j={0,1}; stage B1(t+1) -> buf D^1 r3
#pragma unroll
  for (int i = 0; i < 8; ++i) afr[i] = *(const bf16x8*)(lA0 + i * 512);
  b0 = *(const bf16x8*)(lB0);
  b1 = *(const bf16x8*)(lB0 + 512);
  STAGE(D ^ 1, 3, gB, k1 + 32);
  bar();
  __builtin_amdgcn_s_setprio(1);
#pragma unroll
  for (int i = 0; i < 8; ++i) {
    acc[i][0] = __builtin_amdgcn_mfma_f32_16x16x32_bf16(afr[i], b0, acc[i][0], 0, 0, 0);
    acc[i][1] = __builtin_amdgcn_mfma_f32_16x16x32_bf16(afr[i], b1, acc[i][1], 0, 0, 0);
  }
  __builtin_amdgcn_s_setprio(0);
  bar();

  // ---- phase 2: ks0, j={2,3} (A-frags held); stage A1(t+1) -> buf D^1 r1
  b0 = *(const bf16x8*)(lB0 + 1024);
  b1 = *(const bf16x8*)(lB0 + 1536);
  STAGE(D ^ 1, 1, gA, k1 + 32);
  bar();
  __builtin_amdgcn_s_setprio(1);
#pragma unroll
  for (int i = 0; i < 8; ++i) {
    acc[i][2] = __builtin_amdgcn_mfma_f32_16x16x32_bf16(afr[i], b0, acc[i][2], 0, 0, 0);
    acc[i][3] = __builtin_amdgcn_mfma_f32_16x16x32_bf16(afr[i], b1, acc[i][3], 0, 0, 0);
  }
  __builtin_amdgcn_s_setprio(0);
  bar();

  // ---- phase 3: ks1, j={0,1}; stage A0(t+2) -> buf D r0 (dead after ph1)
#pragma unroll
  for (int i = 0; i < 8; ++i) afr[i] = *(const bf16x8*)(lA1 + i * 512);
  b0 = *(const bf16x8*)(lB1);
  b1 = *(const bf16x8*)(lB1 + 512);
  STAGE(D, 0, gA, k2);
  bar();
  __builtin_amdgcn_s_setprio(1);
#pragma unroll
  for (int i = 0; i < 8; ++i) {
    acc[i][0] = __builtin_amdgcn_mfma_f32_16x16x32_bf16(afr[i], b0, acc[i][0], 0, 0, 0);
    acc[i][1] = __builtin_amdgcn_mfma_f32_16x16x32_bf16(afr[i], b1, acc[i][1], 0, 0, 0);
  }
  __builtin_amdgcn_s_setprio(0);
  bar();

  // ---- phase 4: ks1, j={2,3}; stage B0(t+2) -> buf D r2 (dead after ph2)
  b0 = *(const bf16x8*)(lB1 + 1024);
  b1 = *(const bf16x8*)(lB1 + 1536);
  STAGE(D, 2, gB, k2);
  bar();
  __builtin_amdgcn_s_setprio(1);
#pragma unroll
  for (int i = 0; i < 8; ++i) {
    acc[i][2] = __builtin_amdgcn_mfma_f32_16x16x32_bf16(afr[i], b0, acc[i][2], 0, 0, 0);
    acc[i][3] = __builtin_amdgcn_mfma_f32_16x16x32_bf16(afr[i], b1, acc[i][3], 0, 0, 0);
  }
  __builtin_amdgcn_s_setprio(0);
  // Once per K-tile: keep next tile's A0/B0 (4 loads) in flight, guarantee
  // everything older (= all 4 halves of tile T+1). Never vmcnt(0) in-loop.
  asm volatile("s_waitcnt vmcnt(4)" ::: "memory");
  bar();
}

__global__ __launch_bounds__(512, 2) void gemm_bt_256(
    const unsigned short* __restrict__ A,   // [8192][2048] bf16 bits (x)
    const unsigned short* __restrict__ B,   // [8192][2048] bf16 bits (W)
    float* __restrict__ C) {                // [8192][8192] fp32
  constexpr int K = 2048, N = 8192, NT = 32;
  __shared__ unsigned short lds[65536];     // 128 KiB: 2 bufs x 4 x 16 KiB

  const int t = threadIdx.x;
  const int l = t & 63;
  const int w = t >> 6;
  const int wm = w >> 2, wn = w & 3;        // 2M x 4N waves

  // T1: XCD-aware swizzle (1024 wgs, 1024%8==0 -> simple form is bijective)
  const int bid = blockIdx.x;
  const int swz = (bid & 7) * 128 + (bid >> 3);
  const int bm = swz >> 5, bn = swz & 31;

  f32x4 acc[8][4] = {};

  // Staging source: thread t covers row (t>>2), 16B chunk (t&3) of a half;
  // source chunk pre-swizzled (dest must stay linear for global_load_lds).
  const int lchunk = (t & 3) ^ ((t >> 5) & 1);   // ^= row bit3
  const unsigned short* gA = A + (size_t)(bm * 256 + (t >> 2)) * K + lchunk * 8;
  const unsigned short* gB = B + (size_t)(bn * 256 + (t >> 2)) * K + lchunk * 8;

  // Frag-read offsets (elements): row*32 + swizzled k-chunk*8.
  // MFMA A/B row = (l&15)+16*i, k-chunk = l>>4; row bit3 = (l>>3)&1.
  const int sc8 = ((l >> 4) ^ ((l >> 3) & 1)) * 8;
  const int aoff = (wm * 128 + (l & 15)) * 32 + sc8;
  const int boff = (wn * 64 + (l & 15)) * 32 + sc8;

  // Prologue: mimic steady-state issue order, then vmcnt(4) => tile0's four
  // halves resident, tile1's A0/B0 (4 loads) in flight.
  STAGE(0, 0, gA, 0);    // A0(0)
  STAGE(0, 2, gB, 0);    // B0(0)
  STAGE(0, 3, gB, 32);   // B1(0)
  STAGE(0, 1, gA, 32);   // A1(0)
  STAGE(1, 0, gA, 64);   // A0(1)
  STAGE(1, 2, gB, 64);   // B0(1)
  asm volatile("s_waitcnt vmcnt(4)" ::: "memory");
  bar();

  for (int T = 0; T < NT; T += 2) {   // 2 K-tiles / iter -> static buffer idx
    ktile<0>(T, lds, acc, gA, gB, t, aoff, boff);
    ktile<1>(T + 1, lds, acc, gA, gB, t, aoff, boff);
  }
  asm volatile("s_waitcnt vmcnt(0)" ::: "memory");  // drain tail dummies

  // Epilogue: C/D layout col=lane&15, row=(lane>>4)*4+reg (m89/m91-verified)
  float* Cp = C + (size_t)(bm * 256 + wm * 128 + ((l >> 4) << 2)) * N
              + bn * 256 + wn * 64 + (l & 15);
#pragma unroll
  for (int i = 0; i < 8; ++i)
#pragma unroll
    for (int j = 0; j < 4; ++j)
#pragma unroll
      for (int r = 0; r < 4; ++r)
        Cp[(size_t)(i * 16 + r) * N + j * 16] = acc[i][j][r];
}

extern "C" void kernel_launch(void* const* d_in, const int* in_sizes, int n_in,
                              void* d_out, int out_size, void* d_ws, size_t ws_size,
                              hipStream_t stream) {
  const float* x     = (const float*)d_in[0];   // [4,2048,2048] fp32
  const int*   gi    = (const int*)d_in[1];     // [8192,2048] int32
  const float* scale = (const float*)d_in[2];   // scalar
  const float* lut   = (const float*)d_in[3];   // [15] fp32
  float* out = (float*)d_out;                   // [4,2048,8192] fp32

  const int M = 8192, N = 8192, K = 2048;
  unsigned short* xb = (unsigned short*)d_ws;          // 32 MiB bf16 x
  unsigned short* wb = xb + (size_t)M * K;             // 32 MiB bf16 W

  long nx = (long)M * K;
  long nw = (long)N * K;
  cvt_x_kernel<<<dim3((unsigned)(nx / (256 * 8))), dim3(256), 0, stream>>>(x, xb, nx);
  dequant_kernel<<<dim3((unsigned)(nw / (256 * 8))), dim3(256), 0, stream>>>(gi, lut, scale, wb, nw);

  gemm_bt_256<<<dim3((M / 256) * (N / 256)), dim3(512), 0, stream>>>(xb, wb, out);
}

// Round 2
// 601.221 us; speedup vs baseline: 1.1084x; 1.0024x over previous
//
#include <hip/hip_runtime.h>
#include <cstdint>

// ---- types ----
typedef short bf16x8 __attribute__((ext_vector_type(8)));        // 8 bf16 in 4 VGPRs
typedef unsigned short u16x8 __attribute__((ext_vector_type(8)));
typedef float f32x4 __attribute__((ext_vector_type(4)));
typedef __attribute__((address_space(3))) uint32_t lds_u32;
typedef const __attribute__((address_space(1))) uint32_t gbl_u32;

// fp32 -> bf16 bits, round-to-nearest-even
__device__ __forceinline__ unsigned short f2bf(float f) {
  union { float f; uint32_t u; } c; c.f = f;
  uint32_t u = c.u;
  return (unsigned short)((u + 0x7fffu + ((u >> 16) & 1u)) >> 16);
}

// ---- x fp32 -> bf16, 8 elems/thread ----
__global__ void cvt_x_kernel(const float* __restrict__ x,
                             unsigned short* __restrict__ y, long n) {
  long t = (long)blockIdx.x * blockDim.x + threadIdx.x;
  long base = t * 8;
  if (base >= n) return;
  const float4* p = (const float4*)(x + base);
  float4 f0 = p[0], f1 = p[1];
  u16x8 v;
  v[0] = f2bf(f0.x); v[1] = f2bf(f0.y); v[2] = f2bf(f0.z); v[3] = f2bf(f0.w);
  v[4] = f2bf(f1.x); v[5] = f2bf(f1.y); v[6] = f2bf(f1.z); v[7] = f2bf(f1.w);
  *(u16x8*)(y + base) = v;
}

// ---- W dequant: bf16(lut[idx] * scale), 8 elems/thread ----
__global__ void dequant_kernel(const int* __restrict__ idx,
                               const float* __restrict__ lut,
                               const float* __restrict__ scale,
                               unsigned short* __restrict__ w, long n) {
  __shared__ unsigned short slut[16];
  if (threadIdx.x < 15) slut[threadIdx.x] = f2bf(lut[threadIdx.x] * scale[0]);
  __syncthreads();
  long t = (long)blockIdx.x * blockDim.x + threadIdx.x;
  long base = t * 8;
  if (base >= n) return;
  const int4* p = (const int4*)(idx + base);
  int4 i0 = p[0], i1 = p[1];
  u16x8 v;
  v[0] = slut[i0.x]; v[1] = slut[i0.y]; v[2] = slut[i0.z]; v[3] = slut[i0.w];
  v[4] = slut[i1.x]; v[5] = slut[i1.y]; v[6] = slut[i1.z]; v[7] = slut[i1.w];
  *(u16x8*)(w + base) = v;
}

// ============================================================================
// bf16 NT-GEMM, 256x256 tile, BK=64, 8 waves (2Mx4N), 8-phase counted-vmcnt
// schedule (T1+T2+T3+T4+T5 per guide §5.5). LDS per buffer: 4 regions of 16 KiB:
//   r0 = A ks0 [256][32], r1 = A ks1, r2 = B ks0, r3 = B ks1   (kstep-major)
//
// T2 bank-conflict swizzle (2-bit XOR involution), fixed from R1:
//   stored_chunk = chunk ^ ((row>>1)&3)       (chunk = 16B unit, 4 per 64B row)
// Frag-read bank-group = 4*(row&1) + (c0 ^ ((row>>1)&3)): row bits {0,1,2}
// enumerate all 8 bank-groups exactly 2x over 16 lanes -> 2 lanes/bank = free
// (m136). R1's 1-bit XOR left a 4-way conflict (2.5e7 SQ_LDS_BANK_CONFLICT).
// Applied on the global SOURCE of global_load_lds (dest stays linear, m104)
// and on the ds_read address (rule 21: both-sides-or-neither).
//
// Staging schedule (tile t, buf d=t&1): ph1->B1(t+1), ph2->A1(t+1),
// ph3->A0(t+2) (region dead after ph1), ph4->B0(t+2) (dead after ph2),
// vmcnt(4) once per K-tile => next tile's 4 halves guaranteed, 2 halves
// (4 loads) stay in flight across the barrier. Tail stages are clamped
// dummies (NOT skipped — they keep the vmcnt counts exact).
// ============================================================================

__device__ __forceinline__ void bar() {
  asm volatile("" ::: "memory");
  __builtin_amdgcn_s_barrier();
  asm volatile("" ::: "memory");
}

// One half-tile = 256 rows x 32 k of A or B: 2 x global_load_lds(16B)/thread.
// dst (u32 units): D*65536B + R*16384B + t*16B; 2nd load = rows 128..255.
#define STAGE(D, R, G, KOFF)                                                  \
  do {                                                                        \
    lds_u32* dst_ = (lds_u32*)(&lds[0]) + (D) * 16384 + (R) * 4096 + t * 4;   \
    const unsigned short* s_ = (G) + (KOFF);                                  \
    __builtin_amdgcn_global_load_lds((gbl_u32*)(s_), dst_, 16, 0, 0);         \
    __builtin_amdgcn_global_load_lds((gbl_u32*)(s_ + (size_t)128 * 2048),     \
                                     dst_ + 2048, 16, 0, 0);                  \
  } while (0)

template <int D>
__device__ __forceinline__ void ktile(int T, unsigned short* lds,
                                      f32x4 (&acc)[8][4],
                                      const unsigned short* gA,
                                      const unsigned short* gB, int t,
                                      int aoff, int boff) {
  constexpr int NT = 32;
  const int c1 = (T + 1 < NT) ? (T + 1) : (NT - 1);
  const int c2 = (T + 2 < NT) ? (T + 2) : (NT - 1);
  const int k1 = c1 * 64, k2 = c2 * 64;

  const unsigned short* lA0 = &lds[D * 32768 + aoff];          // A ks0
  const unsigned short* lA1 = &lds[D * 32768 + 8192 + aoff];   // A ks1
  const unsigned short* lB0 = &lds[D * 32768 + 16384 + boff];  // B ks0
  const unsigned short* lB1 = &lds[D * 32768 + 24576 + boff];  // B ks1

  bf16x8 afr[8], b0, b1;

  // ---- phase 1: ks0, j={0,1}; stage B1(t+1) -> buf D^1 r3
#pragma unroll
  for (int i = 0; i < 8; ++i) afr[i] = *(const bf16x8*)(lA0 + i * 512);
  b0 = *(const bf16x8*)(lB0);
  b1 = *(const bf16x8*)(lB0 + 512);
  STAGE(D ^ 1, 3, gB, k1 + 32);
  bar();
  __builtin_amdgcn_s_setprio(1);
#pragma unroll
  for (int i = 0; i < 8; ++i) {
    acc[i][0] = __builtin_amdgcn_mfma_f32_16x16x32_bf16(afr[i], b0, acc[i][0], 0, 0, 0);
    acc[i][1] = __builtin_amdgcn_mfma_f32_16x16x32_bf16(afr[i], b1, acc[i][1], 0, 0, 0);
  }
  __builtin_amdgcn_s_setprio(0);
  bar();

  // ---- phase 2: ks0, j={2,3} (A-frags held); stage A1(t+1) -> buf D^1 r1
  b0 = *(const bf16x8*)(lB0 + 1024);
  b1 = *(const bf16x8*)(lB0 + 1536);
  STAGE(D ^ 1, 1, gA, k1 + 32);
  bar();
  __builtin_amdgcn_s_setprio(1);
#pragma unroll
  for (int i = 0; i < 8; ++i) {
    acc[i][2] = __builtin_amdgcn_mfma_f32_16x16x32_bf16(afr[i], b0, acc[i][2], 0, 0, 0);
    acc[i][3] = __builtin_amdgcn_mfma_f32_16x16x32_bf16(afr[i], b1, acc[i][3], 0, 0, 0);
  }
  __builtin_amdgcn_s_setprio(0);
  bar();

  // ---- phase 3: ks1, j={0,1}; stage A0(t+2) -> buf D r0 (dead after ph1)
#pragma unroll
  for (int i = 0; i < 8; ++i) afr[i] = *(const bf16x8*)(lA1 + i * 512);
  b0 = *(const bf16x8*)(lB1);
  b1 = *(const bf16x8*)(lB1 + 512);
  STAGE(D, 0, gA, k2);
  bar();
  __builtin_amdgcn_s_setprio(1);
#pragma unroll
  for (int i = 0; i < 8; ++i) {
    acc[i][0] = __builtin_amdgcn_mfma_f32_16x16x32_bf16(afr[i], b0, acc[i][0], 0, 0, 0);
    acc[i][1] = __builtin_amdgcn_mfma_f32_16x16x32_bf16(afr[i], b1, acc[i][1], 0, 0, 0);
  }
  __builtin_amdgcn_s_setprio(0);
  bar();

  // ---- phase 4: ks1, j={2,3}; stage B0(t+2) -> buf D r2 (dead after ph2)
  b0 = *(const bf16x8*)(lB1 + 1024);
  b1 = *(const bf16x8*)(lB1 + 1536);
  STAGE(D, 2, gB, k2);
  bar();
  __builtin_amdgcn_s_setprio(1);
#pragma unroll
  for (int i = 0; i < 8; ++i) {
    acc[i][2] = __builtin_amdgcn_mfma_f32_16x16x32_bf16(afr[i], b0, acc[i][2], 0, 0, 0);
    acc[i][3] = __builtin_amdgcn_mfma_f32_16x16x32_bf16(afr[i], b1, acc[i][3], 0, 0, 0);
  }
  __builtin_amdgcn_s_setprio(0);
  // Once per K-tile: keep next tile's A0/B0 (4 loads) in flight, guarantee
  // everything older (= all 4 halves of tile T+1). Never vmcnt(0) in-loop.
  asm volatile("s_waitcnt vmcnt(4)" ::: "memory");
  bar();
}

__global__ __launch_bounds__(512, 2) void gemm_bt_256(
    const unsigned short* __restrict__ A,   // [8192][2048] bf16 bits (x)
    const unsigned short* __restrict__ B,   // [8192][2048] bf16 bits (W)
    float* __restrict__ C) {                // [8192][8192] fp32
  constexpr int K = 2048, N = 8192, NT = 32;
  __shared__ unsigned short lds[65536];     // 128 KiB: 2 bufs x 4 x 16 KiB

  const int t = threadIdx.x;
  const int l = t & 63;
  const int w = t >> 6;
  const int wm = w >> 2, wn = w & 3;        // 2M x 4N waves

  // T1: XCD-aware swizzle (1024 wgs, 1024%8==0 -> simple form is bijective)
  const int bid = blockIdx.x;
  const int swz = (bid & 7) * 128 + (bid >> 3);
  const int bm = swz >> 5, bn = swz & 31;

  f32x4 acc[8][4] = {};

  // Staging source: thread t covers row (t>>2), 16B chunk (t&3) of a half;
  // SOURCE chunk pre-swizzled by the involution: lchunk = (t&3) ^ g(row),
  // g(row) = (row>>1)&3 = (t>>3)&3. (dest must stay linear for global_load_lds;
  // second half row+128 leaves row bits 1-2 unchanged -> same g.)
  const int lchunk = (t & 3) ^ ((t >> 3) & 3);
  const unsigned short* gA = A + (size_t)(bm * 256 + (t >> 2)) * K + lchunk * 8;
  const unsigned short* gB = B + (size_t)(bn * 256 + (t >> 2)) * K + lchunk * 8;

  // Frag-read offsets (elements): row*32 + swizzled k-chunk*8.
  // MFMA A/B row = (l&15)+16*i (+wave offset: multiples of 16 -> row bits 1-2
  // come from l only), k-chunk c0 = l>>4; stored chunk = c0 ^ ((l>>1)&3).
  const int sc8 = ((l >> 4) ^ ((l >> 1) & 3)) * 8;
  const int aoff = (wm * 128 + (l & 15)) * 32 + sc8;
  const int boff = (wn * 64 + (l & 15)) * 32 + sc8;

  // Prologue: mimic steady-state issue order, then vmcnt(4) => tile0's four
  // halves resident, tile1's A0/B0 (4 loads) in flight.
  STAGE(0, 0, gA, 0);    // A0(0)
  STAGE(0, 2, gB, 0);    // B0(0)
  STAGE(0, 3, gB, 32);   // B1(0)
  STAGE(0, 1, gA, 32);   // A1(0)
  STAGE(1, 0, gA, 64);   // A0(1)
  STAGE(1, 2, gB, 64);   // B0(1)
  asm volatile("s_waitcnt vmcnt(4)" ::: "memory");
  bar();

  for (int T = 0; T < NT; T += 2) {   // 2 K-tiles / iter -> static buffer idx
    ktile<0>(T, lds, acc, gA, gB, t, aoff, boff);
    ktile<1>(T + 1, lds, acc, gA, gB, t, aoff, boff);
  }
  asm volatile("s_waitcnt vmcnt(0)" ::: "memory");  // drain tail dummies

  // Epilogue: C/D layout col=lane&15, row=(lane>>4)*4+reg (m89/m91-verified)
  float* Cp = C + (size_t)(bm * 256 + wm * 128 + ((l >> 4) << 2)) * N
              + bn * 256 + wn * 64 + (l & 15);
#pragma unroll
  for (int i = 0; i < 8; ++i)
#pragma unroll
    for (int j = 0; j < 4; ++j)
#pragma unroll
      for (int r = 0; r < 4; ++r)
        Cp[(size_t)(i * 16 + r) * N + j * 16] = acc[i][j][r];
}

extern "C" void kernel_launch(void* const* d_in, const int* in_sizes, int n_in,
                              void* d_out, int out_size, void* d_ws, size_t ws_size,
                              hipStream_t stream) {
  const float* x     = (const float*)d_in[0];   // [4,2048,2048] fp32
  const int*   gi    = (const int*)d_in[1];     // [8192,2048] int32
  const float* scale = (const float*)d_in[2];   // scalar
  const float* lut   = (const float*)d_in[3];   // [15] fp32
  float* out = (float*)d_out;                   // [4,2048,8192] fp32

  const int M = 8192, N = 8192, K = 2048;
  unsigned short* xb = (unsigned short*)d_ws;          // 32 MiB bf16 x
  unsigned short* wb = xb + (size_t)M * K;             // 32 MiB bf16 W

  long nx = (long)M * K;
  long nw = (long)N * K;
  cvt_x_kernel<<<dim3((unsigned)(nx / (256 * 8))), dim3(256), 0, stream>>>(x, xb, nx);
  dequant_kernel<<<dim3((unsigned)(nw / (256 * 8))), dim3(256), 0, stream>>>(gi, lut, scale, wb, nw);

  gemm_bt_256<<<dim3((M / 256) * (N / 256)), dim3(512), 0, stream>>>(xb, wb, out);
}